// Round 1
// baseline (893.123 us; speedup 1.0000x reference)
//
#include <hip/hip_runtime.h>
#include <stdint.h>

// ---------------------------------------------------------------------------
// Decoder block: emb-gather+affine -> causal conv(K=3) -> relu -> GLU(softmax)
//                -> map matmul (+) cross-attention (QK^T softmax PV)
// Shapes: V=50257 E=256 H=256 2H=512 K=3 T=1024 B=32 S=1024 L=1023
// Output: (32, 1023, 512) f32
// All heavy matmuls in bf16 MFMA (16x16x32), fp32 accum.
// Workspace layout (bytes):
//   Xbf   [32][1024][512] bf16 @ 0          (33,554,432)
//   Ybf   [32][1024][512] bf16 @ 33554432   (33,554,432)
//   dec   [32][1024][256] bf16 @ 67108864   (16,777,216)
//   encb  [32][1024][256] bf16 @ 83886080   (16,777,216)
//   vtb   [32][512][1024] bf16 @ 100663296  (33,554,432)  (V transposed)
//   wcb   [512][1536]     bf16 @ 134217728  ( 1,572,864)
//   mwb   [512][256]      bf16 @ 135790592  (   262,144)
//   scb   [32][1024][1024]bf16 @ 136052736  (67,108,864)  (scores)
//   rs    [32][1024]      f32  @ 203161600  (   131,072)
//   total 203,292,672 bytes (~194 MB)
// ---------------------------------------------------------------------------

typedef __bf16 bf16x8_t __attribute__((ext_vector_type(8)));
typedef float  f32x4_t  __attribute__((ext_vector_type(4)));

#define DEV __device__ __forceinline__

DEV unsigned short f2bf(float f) {
  union { float f; unsigned u; } v; v.f = f;
  unsigned r = v.u + 0x7fffu + ((v.u >> 16) & 1u);
  return (unsigned short)(r >> 16);
}
DEV float bf2f(unsigned short u) {
  union { unsigned u; float f; } v; v.u = ((unsigned)u) << 16;
  return v.f;
}

// -------------------------- f32 -> bf16 copy -------------------------------
__global__ __launch_bounds__(256) void cvt_bf16_k(const float* __restrict__ src,
                                                  unsigned short* __restrict__ dst,
                                                  int n) {
  int i = (blockIdx.x * 256 + threadIdx.x) * 4;
  if (i >= n) return;
  float4 v = *(const float4*)(src + i);
  ushort4 o;
  o.x = f2bf(v.x); o.y = f2bf(v.y); o.z = f2bf(v.z); o.w = f2bf(v.w);
  *(ushort4*)(dst + i) = o;
}

// ------------------- V: f32 [b][s][d] -> bf16 [b][d][s] --------------------
__global__ __launch_bounds__(256) void cvt_transpose_v_k(const float* __restrict__ src,
                                                         unsigned short* __restrict__ dst) {
  __shared__ float tile[32][33];
  int b = blockIdx.z, s0 = blockIdx.x * 32, d0 = blockIdx.y * 32;
  int tx = threadIdx.x & 31, ty = threadIdx.x >> 5;
  const float* p = src + ((size_t)b * 1024 + s0) * 512 + d0;
  for (int r = ty; r < 32; r += 8) tile[r][tx] = p[(size_t)r * 512 + tx];
  __syncthreads();
  unsigned short* q = dst + ((size_t)b * 512 + d0) * 1024 + s0;
  for (int r = ty; r < 32; r += 8) q[(size_t)r * 1024 + tx] = f2bf(tile[tx][r]);
}

// ------------- X[b][t][c] = emb[target[t,b]] @ affine_w^T + b --------------
// grid 1024 blocks x 256 thr; each block: 32 rows (t,b), all 512 outputs.
__global__ __launch_bounds__(256) void embed_affine_k(const int* __restrict__ tgt,
                                                      const float* __restrict__ emb,
                                                      const float* __restrict__ aw,
                                                      const float* __restrict__ ab,
                                                      unsigned short* __restrict__ X) {
  __shared__ float xr[32][256];
  const int r0 = blockIdx.x * 32;
  const int tid = threadIdx.x;
  for (int idx = tid; idx < 32 * 64; idx += 256) {
    int r = idx >> 6, c4 = (idx & 63) * 4;
    int row = tgt[r0 + r];
    *(float4*)&xr[r][c4] = *(const float4*)&emb[(size_t)row * 256 + c4];
  }
  __syncthreads();
  const int c0 = tid, c1 = tid + 256;
  float acc0[32], acc1[32];
#pragma unroll
  for (int r = 0; r < 32; ++r) { acc0[r] = 0.f; acc1[r] = 0.f; }
  for (int e = 0; e < 256; e += 4) {
    float4 w0 = *(const float4*)&aw[(size_t)c0 * 256 + e];
    float4 w1 = *(const float4*)&aw[(size_t)c1 * 256 + e];
#pragma unroll
    for (int r = 0; r < 32; ++r) {
      float4 x = *(const float4*)&xr[r][e];
      acc0[r] += x.x * w0.x + x.y * w0.y + x.z * w0.z + x.w * w0.w;
      acc1[r] += x.x * w1.x + x.y * w1.y + x.z * w1.z + x.w * w1.w;
    }
  }
  float b0 = ab[c0], b1 = ab[c1];
  for (int r = 0; r < 32; ++r) {
    int rid = r0 + r, t = rid >> 5, b = rid & 31;
    size_t base = ((size_t)(b * 1024 + t)) << 9;
    X[base + c0] = f2bf(acc0[r] + b0);
    X[base + c1] = f2bf(acc1[r] + b1);
  }
}

// ---- conv: Y[b][l][o] = relu(cb[o] + sum_{i,c} X[b][l-2+i][c] W[o][i*512+c])
// grid (32 ltiles, 32 b) x 256 thr. M=32(l) N=512(o) K=1536. X band in LDS.
__global__ __launch_bounds__(256) void conv_relu_k(const unsigned short* __restrict__ X,
                                                   const unsigned short* __restrict__ Wc,
                                                   const float* __restrict__ cb,
                                                   unsigned short* __restrict__ Y) {
  constexpr int LP = 520;  // padded LDS row stride (bf16 elems): 1040B, 16B-aligned
  __shared__ unsigned short xs[34 * LP];
  const int b = blockIdx.y, l0 = blockIdx.x * 32;
  const int tid = threadIdx.x;
  const int lane = tid & 63, w = tid >> 6, q = lane >> 4, ln = lane & 15;
  // stage band rows t = l0-2 .. l0+31 (zero-fill t<0)
  for (int idx = tid; idx < 34 * 64; idx += 256) {
    int r = idx >> 6, ch = idx & 63;
    int t = l0 - 2 + r;
    uint4 v = make_uint4(0u, 0u, 0u, 0u);
    if (t >= 0) v = *(const uint4*)(X + (((size_t)b * 1024 + t) << 9) + ch * 8);
    *(uint4*)(xs + r * LP + ch * 8) = v;
  }
  __syncthreads();
  f32x4_t acc[2][8];
#pragma unroll
  for (int mt = 0; mt < 2; ++mt)
#pragma unroll
    for (int nt = 0; nt < 8; ++nt) acc[mt][nt] = (f32x4_t){0.f, 0.f, 0.f, 0.f};
  for (int kk = 0; kk < 1536; kk += 32) {
    const int i = kk >> 9, c0 = kk & 511;
    bf16x8_t a[2], bb[8];
#pragma unroll
    for (int mt = 0; mt < 2; ++mt)
      a[mt] = *(const bf16x8_t*)(xs + (mt * 16 + ln + i) * LP + c0 + q * 8);
#pragma unroll
    for (int nt = 0; nt < 8; ++nt) {
      int o = ((w * 8 + nt) << 4) + ln;
      bb[nt] = *(const bf16x8_t*)(Wc + (size_t)o * 1536 + kk + q * 8);
    }
#pragma unroll
    for (int mt = 0; mt < 2; ++mt)
#pragma unroll
      for (int nt = 0; nt < 8; ++nt)
        acc[mt][nt] = __builtin_amdgcn_mfma_f32_16x16x32_bf16(a[mt], bb[nt], acc[mt][nt], 0, 0, 0);
  }
#pragma unroll
  for (int nt = 0; nt < 8; ++nt) {
    const int o = ((w * 8 + nt) << 4) + ln;
    const float bias = cb[o];
#pragma unroll
    for (int mt = 0; mt < 2; ++mt)
#pragma unroll
      for (int r = 0; r < 4; ++r) {
        int l = l0 + mt * 16 + q * 4 + r;
        float v = acc[mt][nt][r] + bias;
        Y[(((size_t)b * 1024 + l) << 9) + o] = f2bf(v > 0.f ? v : 0.f);
      }
  }
}

// ---- GLU: dec[b][l][h] = A[h] * softmax_h(Bg)[h], one wave per (b,l) row ---
__global__ __launch_bounds__(256) void glu_k(const unsigned short* __restrict__ Y,
                                             unsigned short* __restrict__ dec) {
  const int row = blockIdx.x * 4 + (threadIdx.x >> 6);
  const int lane = threadIdx.x & 63;
  const unsigned short* p = Y + ((size_t)row << 9);
  ushort4 av = *(const ushort4*)(p + lane * 4);
  ushort4 gv = *(const ushort4*)(p + 256 + lane * 4);
  // values are small (|x| < ~0.05): exp without max-subtraction is safe
  float e0 = __expf(bf2f(gv.x)), e1 = __expf(bf2f(gv.y));
  float e2 = __expf(bf2f(gv.z)), e3 = __expf(bf2f(gv.w));
  float s = e0 + e1 + e2 + e3;
#pragma unroll
  for (int off = 32; off > 0; off >>= 1) s += __shfl_xor(s, off);
  float inv = 1.f / s;
  ushort4 o;
  o.x = f2bf(bf2f(av.x) * e0 * inv);
  o.y = f2bf(bf2f(av.y) * e1 * inv);
  o.z = f2bf(bf2f(av.z) * e2 * inv);
  o.w = f2bf(bf2f(av.w) * e3 * inv);
  *(ushort4*)(dec + ((size_t)row << 8) + lane * 4) = o;
}

// -------- dec2 = dec @ map_w^T + map_b  -> writes d_out (l < 1023) ---------
__global__ __launch_bounds__(256) void map_gemm_k(const unsigned short* __restrict__ dec,
                                                  const unsigned short* __restrict__ mw,
                                                  const float* __restrict__ mb,
                                                  float* __restrict__ out) {
  const int b = blockIdx.y, l0 = blockIdx.x * 32;
  const int tid = threadIdx.x, lane = tid & 63, w = tid >> 6, q = lane >> 4, ln = lane & 15;
  f32x4_t acc[2][8];
#pragma unroll
  for (int mt = 0; mt < 2; ++mt)
#pragma unroll
    for (int nt = 0; nt < 8; ++nt) acc[mt][nt] = (f32x4_t){0.f, 0.f, 0.f, 0.f};
  for (int kk = 0; kk < 256; kk += 32) {
    bf16x8_t a[2], bb[8];
#pragma unroll
    for (int mt = 0; mt < 2; ++mt)
      a[mt] = *(const bf16x8_t*)(dec + (((size_t)b * 1024 + l0 + mt * 16 + ln) << 8) + kk + q * 8);
#pragma unroll
    for (int nt = 0; nt < 8; ++nt) {
      int n = ((w * 8 + nt) << 4) + ln;
      bb[nt] = *(const bf16x8_t*)(mw + ((size_t)n << 8) + kk + q * 8);
    }
#pragma unroll
    for (int mt = 0; mt < 2; ++mt)
#pragma unroll
      for (int nt = 0; nt < 8; ++nt)
        acc[mt][nt] = __builtin_amdgcn_mfma_f32_16x16x32_bf16(a[mt], bb[nt], acc[mt][nt], 0, 0, 0);
  }
#pragma unroll
  for (int nt = 0; nt < 8; ++nt) {
    const int n = ((w * 8 + nt) << 4) + ln;
    const float bias = mb[n];
#pragma unroll
    for (int mt = 0; mt < 2; ++mt)
#pragma unroll
      for (int r = 0; r < 4; ++r) {
        int l = l0 + mt * 16 + q * 4 + r;
        if (l < 1023) out[((size_t)b * 1023 + l) * 512 + n] = acc[mt][nt][r] + bias;
      }
  }
}

// -------- scores[b][l][s] = dec[b][l][:] . enc[b][s][:]  (bf16 out) --------
__global__ __launch_bounds__(256) void scores_k(const unsigned short* __restrict__ dec,
                                                const unsigned short* __restrict__ enc,
                                                unsigned short* __restrict__ sc) {
  const int b = blockIdx.z, nb = blockIdx.y, l0 = blockIdx.x * 32;
  const int tid = threadIdx.x, lane = tid & 63, w = tid >> 6, q = lane >> 4, ln = lane & 15;
  f32x4_t acc[2][8];
#pragma unroll
  for (int mt = 0; mt < 2; ++mt)
#pragma unroll
    for (int nt = 0; nt < 8; ++nt) acc[mt][nt] = (f32x4_t){0.f, 0.f, 0.f, 0.f};
  for (int kk = 0; kk < 256; kk += 32) {
    bf16x8_t a[2], bb[8];
#pragma unroll
    for (int mt = 0; mt < 2; ++mt)
      a[mt] = *(const bf16x8_t*)(dec + (((size_t)b * 1024 + l0 + mt * 16 + ln) << 8) + kk + q * 8);
#pragma unroll
    for (int nt = 0; nt < 8; ++nt) {
      int s = nb * 512 + ((w * 8 + nt) << 4) + ln;
      bb[nt] = *(const bf16x8_t*)(enc + (((size_t)b * 1024 + s) << 8) + kk + q * 8);
    }
#pragma unroll
    for (int mt = 0; mt < 2; ++mt)
#pragma unroll
      for (int nt = 0; nt < 8; ++nt)
        acc[mt][nt] = __builtin_amdgcn_mfma_f32_16x16x32_bf16(a[mt], bb[nt], acc[mt][nt], 0, 0, 0);
  }
#pragma unroll
  for (int nt = 0; nt < 8; ++nt) {
    const int s = nb * 512 + ((w * 8 + nt) << 4) + ln;
#pragma unroll
    for (int mt = 0; mt < 2; ++mt)
#pragma unroll
      for (int r = 0; r < 4; ++r) {
        int l = l0 + mt * 16 + q * 4 + r;
        sc[(((size_t)b * 1024 + l) << 10) + s] = f2bf(acc[mt][nt][r]);
      }
  }
}

// ------------- rs[b*1024+l] = sum_s exp(scores)  (one wave/row) ------------
DEV float exp2sum(unsigned u) { return __expf(bf2f((unsigned short)(u & 0xffffu))) +
                                       __expf(bf2f((unsigned short)(u >> 16))); }
__global__ __launch_bounds__(256) void rowsum_k(const unsigned short* __restrict__ sc,
                                                float* __restrict__ rs) {
  const int row = blockIdx.x * 4 + (threadIdx.x >> 6);
  const int lane = threadIdx.x & 63;
  const unsigned short* p = sc + (((size_t)row) << 10) + lane * 16;
  uint4 v0 = *(const uint4*)p;
  uint4 v1 = *(const uint4*)(p + 8);
  float s = exp2sum(v0.x) + exp2sum(v0.y) + exp2sum(v0.z) + exp2sum(v0.w) +
            exp2sum(v1.x) + exp2sum(v1.y) + exp2sum(v1.z) + exp2sum(v1.w);
#pragma unroll
  for (int off = 32; off > 0; off >>= 1) s += __shfl_xor(s, off);
  if (lane == 0) rs[row] = s;
}

// ------- out[b][l][:] += softmax(scores) @ V   (P built on the fly) --------
__global__ __launch_bounds__(256) void attn_pv_k(const unsigned short* __restrict__ sc,
                                                 const float* __restrict__ rs,
                                                 const unsigned short* __restrict__ vt,
                                                 float* __restrict__ out) {
  const int b = blockIdx.y, l0 = blockIdx.x * 32;
  const int tid = threadIdx.x, lane = tid & 63, w = tid >> 6, q = lane >> 4, ln = lane & 15;
  float rinv[2];
#pragma unroll
  for (int mt = 0; mt < 2; ++mt) rinv[mt] = 1.f / rs[b * 1024 + l0 + mt * 16 + ln];
  f32x4_t acc[2][8];
#pragma unroll
  for (int mt = 0; mt < 2; ++mt)
#pragma unroll
    for (int nt = 0; nt < 8; ++nt) acc[mt][nt] = (f32x4_t){0.f, 0.f, 0.f, 0.f};
  for (int kk = 0; kk < 1024; kk += 32) {
    bf16x8_t a[2], bb[8];
#pragma unroll
    for (int mt = 0; mt < 2; ++mt) {
      const unsigned short* p =
          sc + (((size_t)b * 1024 + l0 + mt * 16 + ln) << 10) + kk + q * 8;
      union { bf16x8_t v; unsigned short u[8]; } fa;
#pragma unroll
      for (int j = 0; j < 8; ++j) fa.u[j] = f2bf(__expf(bf2f(p[j])) * rinv[mt]);
      a[mt] = fa.v;
    }
#pragma unroll
    for (int nt = 0; nt < 8; ++nt) {
      int d = ((w * 8 + nt) << 4) + ln;
      bb[nt] = *(const bf16x8_t*)(vt + (((size_t)b * 512 + d) << 10) + kk + q * 8);
    }
#pragma unroll
    for (int mt = 0; mt < 2; ++mt)
#pragma unroll
      for (int nt = 0; nt < 8; ++nt)
        acc[mt][nt] = __builtin_amdgcn_mfma_f32_16x16x32_bf16(a[mt], bb[nt], acc[mt][nt], 0, 0, 0);
  }
#pragma unroll
  for (int nt = 0; nt < 8; ++nt) {
    const int d = ((w * 8 + nt) << 4) + ln;
#pragma unroll
    for (int mt = 0; mt < 2; ++mt)
#pragma unroll
      for (int r = 0; r < 4; ++r) {
        int l = l0 + mt * 16 + q * 4 + r;
        if (l < 1023) {
          size_t off = ((size_t)b * 1023 + l) * 512 + d;
          out[off] += acc[mt][nt][r];
        }
      }
  }
}

// ---------------------------------------------------------------------------
extern "C" void kernel_launch(void* const* d_in, const int* in_sizes, int n_in,
                              void* d_out, int out_size, void* d_ws, size_t ws_size,
                              hipStream_t stream) {
  const int*   target = (const int*)d_in[1];
  const float* enc    = (const float*)d_in[2];
  const float* src    = (const float*)d_in[3];
  const float* emb    = (const float*)d_in[4];
  const float* aw     = (const float*)d_in[5];
  const float* ab     = (const float*)d_in[6];
  const float* cw     = (const float*)d_in[7];
  const float* cb     = (const float*)d_in[8];
  const float* mw     = (const float*)d_in[9];
  const float* mb     = (const float*)d_in[10];
  float* out = (float*)d_out;
  char* ws = (char*)d_ws;

  unsigned short* Xbf  = (unsigned short*)(ws);
  unsigned short* Ybf  = (unsigned short*)(ws + 33554432);
  unsigned short* dec  = (unsigned short*)(ws + 67108864);
  unsigned short* encb = (unsigned short*)(ws + 83886080);
  unsigned short* vtb  = (unsigned short*)(ws + 100663296);
  unsigned short* wcb  = (unsigned short*)(ws + 134217728);
  unsigned short* mwb  = (unsigned short*)(ws + 135790592);
  unsigned short* scb  = (unsigned short*)(ws + 136052736);
  float*          rs   = (float*)(ws + 203161600);

  cvt_bf16_k<<<8192, 256, 0, stream>>>(enc, encb, 32 * 1024 * 256);
  cvt_bf16_k<<<768, 256, 0, stream>>>(cw, wcb, 512 * 1536);
  cvt_bf16_k<<<128, 256, 0, stream>>>(mw, mwb, 512 * 256);
  cvt_transpose_v_k<<<dim3(32, 16, 32), 256, 0, stream>>>(src, vtb);
  embed_affine_k<<<1024, 256, 0, stream>>>(target, emb, aw, ab, Xbf);
  conv_relu_k<<<dim3(32, 32), 256, 0, stream>>>(Xbf, wcb, cb, Ybf);
  glu_k<<<8192, 256, 0, stream>>>(Ybf, dec);
  map_gemm_k<<<dim3(32, 32), 256, 0, stream>>>(dec, mwb, mb, out);
  scores_k<<<dim3(32, 2, 32), 256, 0, stream>>>(dec, encb, scb);
  rowsum_k<<<8192, 256, 0, stream>>>(scb, rs);
  attn_pv_k<<<dim3(32, 32), 256, 0, stream>>>(scb, rs, vtb, out);
}

// Round 2
// 772.362 us; speedup vs baseline: 1.1564x; 1.1564x over previous
//
#include <hip/hip_runtime.h>
#include <stdint.h>

// ---------------------------------------------------------------------------
// Decoder block: emb-gather+affine -> causal conv(K=3) -> relu -> GLU(softmax)
//                -> map matmul (+) cross-attention (QK^T softmax PV)
// Shapes: V=50257 E=256 H=256 2H=512 K=3 T=1024 B=32 S=1024 L=1023
// Output: (32, 1023, 512) f32
// All heavy matmuls in bf16 MFMA (16x16x32), fp32 accum.
// R2: embed_affine -> MFMA; scores stores exp(score); PV normalizes post-GEMM.
// Workspace layout (bytes):
//   Xbf   [32][1024][512] bf16 @ 0          (33,554,432)
//   Ybf   [32][1024][512] bf16 @ 33554432   (33,554,432)
//   dec   [32][1024][256] bf16 @ 67108864   (16,777,216)
//   encb  [32][1024][256] bf16 @ 83886080   (16,777,216)
//   vtb   [32][512][1024] bf16 @ 100663296  (33,554,432)  (V transposed)
//   wcb   [512][1536]     bf16 @ 134217728  ( 1,572,864)
//   mwb   [512][256]      bf16 @ 135790592  (   262,144)
//   scb   [32][1024][1024]bf16 @ 136052736  (67,108,864)  (exp-scores)
//   rs    [32][1024]      f32  @ 203161600  (   131,072)
//   awb aliases scb (512x256 bf16) — consumed by embed_affine before scores_k
// ---------------------------------------------------------------------------

typedef __bf16 bf16x8_t __attribute__((ext_vector_type(8)));
typedef float  f32x4_t  __attribute__((ext_vector_type(4)));

#define DEV __device__ __forceinline__

DEV unsigned short f2bf(float f) {
  union { float f; unsigned u; } v; v.f = f;
  unsigned r = v.u + 0x7fffu + ((v.u >> 16) & 1u);
  return (unsigned short)(r >> 16);
}
DEV float bf2f(unsigned short u) {
  union { unsigned u; float f; } v; v.u = ((unsigned)u) << 16;
  return v.f;
}

// -------------------------- f32 -> bf16 copy -------------------------------
__global__ __launch_bounds__(256) void cvt_bf16_k(const float* __restrict__ src,
                                                  unsigned short* __restrict__ dst,
                                                  int n) {
  int i = (blockIdx.x * 256 + threadIdx.x) * 4;
  if (i >= n) return;
  float4 v = *(const float4*)(src + i);
  ushort4 o;
  o.x = f2bf(v.x); o.y = f2bf(v.y); o.z = f2bf(v.z); o.w = f2bf(v.w);
  *(ushort4*)(dst + i) = o;
}

// ------------------- V: f32 [b][s][d] -> bf16 [b][d][s] --------------------
__global__ __launch_bounds__(256) void cvt_transpose_v_k(const float* __restrict__ src,
                                                         unsigned short* __restrict__ dst) {
  __shared__ float tile[32][33];
  int b = blockIdx.z, s0 = blockIdx.x * 32, d0 = blockIdx.y * 32;
  int tx = threadIdx.x & 31, ty = threadIdx.x >> 5;
  const float* p = src + ((size_t)b * 1024 + s0) * 512 + d0;
  for (int r = ty; r < 32; r += 8) tile[r][tx] = p[(size_t)r * 512 + tx];
  __syncthreads();
  unsigned short* q = dst + ((size_t)b * 512 + d0) * 1024 + s0;
  for (int r = ty; r < 32; r += 8) q[(size_t)r * 1024 + tx] = f2bf(tile[tx][r]);
}

// ------ X[b][t][c] = bf16( emb[target[t,b]] @ affine_w^T + affine_b ) ------
// MFMA version: per block 32 rows x 512 outs, K=256. A gathered->bf16 in LDS.
__global__ __launch_bounds__(256) void embed_affine_k(const int* __restrict__ tgt,
                                                      const float* __restrict__ emb,
                                                      const unsigned short* __restrict__ awb,
                                                      const float* __restrict__ ab,
                                                      unsigned short* __restrict__ X) {
  constexpr int AP = 264;  // padded LDS row stride (bf16): 528B, 16B-aligned, 4-bank skew
  __shared__ unsigned short xs[32 * AP];
  const int r0 = blockIdx.x * 32;
  const int tid = threadIdx.x;
  // gather 32 emb rows (f32), convert to bf16 into LDS
  for (int idx = tid; idx < 32 * 64; idx += 256) {
    int r = idx >> 6, c4 = (idx & 63) * 4;
    int row = tgt[r0 + r];
    float4 v = *(const float4*)&emb[(size_t)row * 256 + c4];
    ushort4 o;
    o.x = f2bf(v.x); o.y = f2bf(v.y); o.z = f2bf(v.z); o.w = f2bf(v.w);
    *(ushort4*)&xs[r * AP + c4] = o;
  }
  __syncthreads();
  const int lane = tid & 63, w = tid >> 6, q = lane >> 4, ln = lane & 15;
  f32x4_t acc[2][8];
#pragma unroll
  for (int mt = 0; mt < 2; ++mt)
#pragma unroll
    for (int nt = 0; nt < 8; ++nt) acc[mt][nt] = (f32x4_t){0.f, 0.f, 0.f, 0.f};
  for (int kk = 0; kk < 256; kk += 32) {
    bf16x8_t a[2], bb[8];
#pragma unroll
    for (int mt = 0; mt < 2; ++mt)
      a[mt] = *(const bf16x8_t*)(xs + (mt * 16 + ln) * AP + kk + q * 8);
#pragma unroll
    for (int nt = 0; nt < 8; ++nt) {
      int n = ((w * 8 + nt) << 4) + ln;
      bb[nt] = *(const bf16x8_t*)(awb + ((size_t)n << 8) + kk + q * 8);
    }
#pragma unroll
    for (int mt = 0; mt < 2; ++mt)
#pragma unroll
      for (int nt = 0; nt < 8; ++nt)
        acc[mt][nt] = __builtin_amdgcn_mfma_f32_16x16x32_bf16(a[mt], bb[nt], acc[mt][nt], 0, 0, 0);
  }
#pragma unroll
  for (int nt = 0; nt < 8; ++nt) {
    const int o = ((w * 8 + nt) << 4) + ln;
    const float bias = ab[o];
#pragma unroll
    for (int mt = 0; mt < 2; ++mt)
#pragma unroll
      for (int r = 0; r < 4; ++r) {
        int rid = r0 + mt * 16 + q * 4 + r;
        int t = rid >> 5, b = rid & 31;
        X[(((size_t)(b * 1024 + t)) << 9) + o] = f2bf(acc[mt][nt][r] + bias);
      }
  }
}

// ---- conv: Y[b][l][o] = relu(cb[o] + sum_{i,c} X[b][l-2+i][c] W[o][i*512+c])
// grid (32 ltiles, 32 b) x 256 thr. M=32(l) N=512(o) K=1536. X band in LDS.
__global__ __launch_bounds__(256) void conv_relu_k(const unsigned short* __restrict__ X,
                                                   const unsigned short* __restrict__ Wc,
                                                   const float* __restrict__ cb,
                                                   unsigned short* __restrict__ Y) {
  constexpr int LP = 520;  // padded LDS row stride (bf16 elems): 1040B, 16B-aligned
  __shared__ unsigned short xs[34 * LP];
  const int b = blockIdx.y, l0 = blockIdx.x * 32;
  const int tid = threadIdx.x;
  const int lane = tid & 63, w = tid >> 6, q = lane >> 4, ln = lane & 15;
  // stage band rows t = l0-2 .. l0+31 (zero-fill t<0)
  for (int idx = tid; idx < 34 * 64; idx += 256) {
    int r = idx >> 6, ch = idx & 63;
    int t = l0 - 2 + r;
    uint4 v = make_uint4(0u, 0u, 0u, 0u);
    if (t >= 0) v = *(const uint4*)(X + (((size_t)b * 1024 + t) << 9) + ch * 8);
    *(uint4*)(xs + r * LP + ch * 8) = v;
  }
  __syncthreads();
  f32x4_t acc[2][8];
#pragma unroll
  for (int mt = 0; mt < 2; ++mt)
#pragma unroll
    for (int nt = 0; nt < 8; ++nt) acc[mt][nt] = (f32x4_t){0.f, 0.f, 0.f, 0.f};
  for (int kk = 0; kk < 1536; kk += 32) {
    const int i = kk >> 9, c0 = kk & 511;
    bf16x8_t a[2], bb[8];
#pragma unroll
    for (int mt = 0; mt < 2; ++mt)
      a[mt] = *(const bf16x8_t*)(xs + (mt * 16 + ln + i) * LP + c0 + q * 8);
#pragma unroll
    for (int nt = 0; nt < 8; ++nt) {
      int o = ((w * 8 + nt) << 4) + ln;
      bb[nt] = *(const bf16x8_t*)(Wc + (size_t)o * 1536 + kk + q * 8);
    }
#pragma unroll
    for (int mt = 0; mt < 2; ++mt)
#pragma unroll
      for (int nt = 0; nt < 8; ++nt)
        acc[mt][nt] = __builtin_amdgcn_mfma_f32_16x16x32_bf16(a[mt], bb[nt], acc[mt][nt], 0, 0, 0);
  }
#pragma unroll
  for (int nt = 0; nt < 8; ++nt) {
    const int o = ((w * 8 + nt) << 4) + ln;
    const float bias = cb[o];
#pragma unroll
    for (int mt = 0; mt < 2; ++mt)
#pragma unroll
      for (int r = 0; r < 4; ++r) {
        int l = l0 + mt * 16 + q * 4 + r;
        float v = acc[mt][nt][r] + bias;
        Y[(((size_t)b * 1024 + l) << 9) + o] = f2bf(v > 0.f ? v : 0.f);
      }
  }
}

// ---- GLU: dec[b][l][h] = A[h] * softmax_h(Bg)[h], one wave per (b,l) row ---
__global__ __launch_bounds__(256) void glu_k(const unsigned short* __restrict__ Y,
                                             unsigned short* __restrict__ dec) {
  const int row = blockIdx.x * 4 + (threadIdx.x >> 6);
  const int lane = threadIdx.x & 63;
  const unsigned short* p = Y + ((size_t)row << 9);
  ushort4 av = *(const ushort4*)(p + lane * 4);
  ushort4 gv = *(const ushort4*)(p + 256 + lane * 4);
  // values are small (|x| < ~0.05): exp without max-subtraction is safe
  float e0 = __expf(bf2f(gv.x)), e1 = __expf(bf2f(gv.y));
  float e2 = __expf(bf2f(gv.z)), e3 = __expf(bf2f(gv.w));
  float s = e0 + e1 + e2 + e3;
#pragma unroll
  for (int off = 32; off > 0; off >>= 1) s += __shfl_xor(s, off);
  float inv = 1.f / s;
  ushort4 o;
  o.x = f2bf(bf2f(av.x) * e0 * inv);
  o.y = f2bf(bf2f(av.y) * e1 * inv);
  o.z = f2bf(bf2f(av.z) * e2 * inv);
  o.w = f2bf(bf2f(av.w) * e3 * inv);
  *(ushort4*)(dec + ((size_t)row << 8) + lane * 4) = o;
}

// -------- dec2 = dec @ map_w^T + map_b  -> writes d_out (l < 1023) ---------
__global__ __launch_bounds__(256) void map_gemm_k(const unsigned short* __restrict__ dec,
                                                  const unsigned short* __restrict__ mw,
                                                  const float* __restrict__ mb,
                                                  float* __restrict__ out) {
  const int b = blockIdx.y, l0 = blockIdx.x * 32;
  const int tid = threadIdx.x, lane = tid & 63, w = tid >> 6, q = lane >> 4, ln = lane & 15;
  f32x4_t acc[2][8];
#pragma unroll
  for (int mt = 0; mt < 2; ++mt)
#pragma unroll
    for (int nt = 0; nt < 8; ++nt) acc[mt][nt] = (f32x4_t){0.f, 0.f, 0.f, 0.f};
  for (int kk = 0; kk < 256; kk += 32) {
    bf16x8_t a[2], bb[8];
#pragma unroll
    for (int mt = 0; mt < 2; ++mt)
      a[mt] = *(const bf16x8_t*)(dec + (((size_t)b * 1024 + l0 + mt * 16 + ln) << 8) + kk + q * 8);
#pragma unroll
    for (int nt = 0; nt < 8; ++nt) {
      int n = ((w * 8 + nt) << 4) + ln;
      bb[nt] = *(const bf16x8_t*)(mw + ((size_t)n << 8) + kk + q * 8);
    }
#pragma unroll
    for (int mt = 0; mt < 2; ++mt)
#pragma unroll
      for (int nt = 0; nt < 8; ++nt)
        acc[mt][nt] = __builtin_amdgcn_mfma_f32_16x16x32_bf16(a[mt], bb[nt], acc[mt][nt], 0, 0, 0);
  }
#pragma unroll
  for (int nt = 0; nt < 8; ++nt) {
    const int n = ((w * 8 + nt) << 4) + ln;
    const float bias = mb[n];
#pragma unroll
    for (int mt = 0; mt < 2; ++mt)
#pragma unroll
      for (int r = 0; r < 4; ++r) {
        int l = l0 + mt * 16 + q * 4 + r;
        if (l < 1023) out[((size_t)b * 1023 + l) * 512 + n] = acc[mt][nt][r] + bias;
      }
  }
}

// ---- sc[b][l][s] = bf16( exp( dec[b][l][:] . enc[b][s][:] ) )  ------------
__global__ __launch_bounds__(256) void scores_k(const unsigned short* __restrict__ dec,
                                                const unsigned short* __restrict__ enc,
                                                unsigned short* __restrict__ sc) {
  const int b = blockIdx.z, nb = blockIdx.y, l0 = blockIdx.x * 32;
  const int tid = threadIdx.x, lane = tid & 63, w = tid >> 6, q = lane >> 4, ln = lane & 15;
  f32x4_t acc[2][8];
#pragma unroll
  for (int mt = 0; mt < 2; ++mt)
#pragma unroll
    for (int nt = 0; nt < 8; ++nt) acc[mt][nt] = (f32x4_t){0.f, 0.f, 0.f, 0.f};
  for (int kk = 0; kk < 256; kk += 32) {
    bf16x8_t a[2], bb[8];
#pragma unroll
    for (int mt = 0; mt < 2; ++mt)
      a[mt] = *(const bf16x8_t*)(dec + (((size_t)b * 1024 + l0 + mt * 16 + ln) << 8) + kk + q * 8);
#pragma unroll
    for (int nt = 0; nt < 8; ++nt) {
      int s = nb * 512 + ((w * 8 + nt) << 4) + ln;
      bb[nt] = *(const bf16x8_t*)(enc + (((size_t)b * 1024 + s) << 8) + kk + q * 8);
    }
#pragma unroll
    for (int mt = 0; mt < 2; ++mt)
#pragma unroll
      for (int nt = 0; nt < 8; ++nt)
        acc[mt][nt] = __builtin_amdgcn_mfma_f32_16x16x32_bf16(a[mt], bb[nt], acc[mt][nt], 0, 0, 0);
  }
  // scores are tiny (|s| < ~0.01): exp without max-subtraction is safe
#pragma unroll
  for (int nt = 0; nt < 8; ++nt) {
    const int s = nb * 512 + ((w * 8 + nt) << 4) + ln;
#pragma unroll
    for (int mt = 0; mt < 2; ++mt)
#pragma unroll
      for (int r = 0; r < 4; ++r) {
        int l = l0 + mt * 16 + q * 4 + r;
        sc[(((size_t)b * 1024 + l) << 10) + s] = f2bf(__expf(acc[mt][nt][r]));
      }
  }
}

// ------------- rs[b*1024+l] = sum_s exp-scores  (one wave/row) -------------
DEV float bfsum2(unsigned u) { return bf2f((unsigned short)(u & 0xffffu)) +
                                      bf2f((unsigned short)(u >> 16)); }
__global__ __launch_bounds__(256) void rowsum_k(const unsigned short* __restrict__ sc,
                                                float* __restrict__ rs) {
  const int row = blockIdx.x * 4 + (threadIdx.x >> 6);
  const int lane = threadIdx.x & 63;
  const unsigned short* p = sc + (((size_t)row) << 10) + lane * 16;
  uint4 v0 = *(const uint4*)p;
  uint4 v1 = *(const uint4*)(p + 8);
  float s = bfsum2(v0.x) + bfsum2(v0.y) + bfsum2(v0.z) + bfsum2(v0.w) +
            bfsum2(v1.x) + bfsum2(v1.y) + bfsum2(v1.z) + bfsum2(v1.w);
#pragma unroll
  for (int off = 32; off > 0; off >>= 1) s += __shfl_xor(s, off);
  if (lane == 0) rs[row] = s;
}

// --- out[b][l][:] += (expS @ V) / rs[l]   (normalization folded post-GEMM) --
__global__ __launch_bounds__(256) void attn_pv_k(const unsigned short* __restrict__ sc,
                                                 const float* __restrict__ rs,
                                                 const unsigned short* __restrict__ vt,
                                                 float* __restrict__ out) {
  const int b = blockIdx.y, l0 = blockIdx.x * 32;
  const int tid = threadIdx.x, lane = tid & 63, w = tid >> 6, q = lane >> 4, ln = lane & 15;
  f32x4_t acc[2][8];
#pragma unroll
  for (int mt = 0; mt < 2; ++mt)
#pragma unroll
    for (int nt = 0; nt < 8; ++nt) acc[mt][nt] = (f32x4_t){0.f, 0.f, 0.f, 0.f};
  for (int kk = 0; kk < 1024; kk += 32) {
    bf16x8_t a[2], bb[8];
#pragma unroll
    for (int mt = 0; mt < 2; ++mt)
      a[mt] = *(const bf16x8_t*)(sc + (((size_t)b * 1024 + l0 + mt * 16 + ln) << 10) + kk + q * 8);
#pragma unroll
    for (int nt = 0; nt < 8; ++nt) {
      int d = ((w * 8 + nt) << 4) + ln;
      bb[nt] = *(const bf16x8_t*)(vt + (((size_t)b * 512 + d) << 10) + kk + q * 8);
    }
#pragma unroll
    for (int mt = 0; mt < 2; ++mt)
#pragma unroll
      for (int nt = 0; nt < 8; ++nt)
        acc[mt][nt] = __builtin_amdgcn_mfma_f32_16x16x32_bf16(a[mt], bb[nt], acc[mt][nt], 0, 0, 0);
  }
  float rinv[2][4];
#pragma unroll
  for (int mt = 0; mt < 2; ++mt)
#pragma unroll
    for (int r = 0; r < 4; ++r)
      rinv[mt][r] = 1.f / rs[b * 1024 + l0 + mt * 16 + q * 4 + r];
#pragma unroll
  for (int nt = 0; nt < 8; ++nt) {
    const int d = ((w * 8 + nt) << 4) + ln;
#pragma unroll
    for (int mt = 0; mt < 2; ++mt)
#pragma unroll
      for (int r = 0; r < 4; ++r) {
        int l = l0 + mt * 16 + q * 4 + r;
        if (l < 1023) {
          size_t off = ((size_t)b * 1023 + l) * 512 + d;
          out[off] += acc[mt][nt][r] * rinv[mt][r];
        }
      }
  }
}

// ---------------------------------------------------------------------------
extern "C" void kernel_launch(void* const* d_in, const int* in_sizes, int n_in,
                              void* d_out, int out_size, void* d_ws, size_t ws_size,
                              hipStream_t stream) {
  const int*   target = (const int*)d_in[1];
  const float* enc    = (const float*)d_in[2];
  const float* src    = (const float*)d_in[3];
  const float* emb    = (const float*)d_in[4];
  const float* aw     = (const float*)d_in[5];
  const float* ab     = (const float*)d_in[6];
  const float* cw     = (const float*)d_in[7];
  const float* cb     = (const float*)d_in[8];
  const float* mw     = (const float*)d_in[9];
  const float* mb     = (const float*)d_in[10];
  float* out = (float*)d_out;
  char* ws = (char*)d_ws;

  unsigned short* Xbf  = (unsigned short*)(ws);
  unsigned short* Ybf  = (unsigned short*)(ws + 33554432);
  unsigned short* dec  = (unsigned short*)(ws + 67108864);
  unsigned short* encb = (unsigned short*)(ws + 83886080);
  unsigned short* vtb  = (unsigned short*)(ws + 100663296);
  unsigned short* wcb  = (unsigned short*)(ws + 134217728);
  unsigned short* mwb  = (unsigned short*)(ws + 135790592);
  unsigned short* scb  = (unsigned short*)(ws + 136052736);
  float*          rs   = (float*)(ws + 203161600);
  // awb aliases the head of scb: used only before scores_k writes scb
  unsigned short* awb  = scb;

  cvt_bf16_k<<<8192, 256, 0, stream>>>(enc, encb, 32 * 1024 * 256);
  cvt_bf16_k<<<768, 256, 0, stream>>>(cw, wcb, 512 * 1536);
  cvt_bf16_k<<<128, 256, 0, stream>>>(mw, mwb, 512 * 256);
  cvt_bf16_k<<<128, 256, 0, stream>>>(aw, awb, 512 * 256);
  cvt_transpose_v_k<<<dim3(32, 16, 32), 256, 0, stream>>>(src, vtb);
  embed_affine_k<<<1024, 256, 0, stream>>>(target, emb, awb, ab, Xbf);
  conv_relu_k<<<dim3(32, 32), 256, 0, stream>>>(Xbf, wcb, cb, Ybf);
  glu_k<<<8192, 256, 0, stream>>>(Ybf, dec);
  map_gemm_k<<<dim3(32, 32), 256, 0, stream>>>(dec, mwb, mb, out);
  scores_k<<<dim3(32, 2, 32), 256, 0, stream>>>(dec, encb, scb);
  rowsum_k<<<8192, 256, 0, stream>>>(scb, rs);
  attn_pv_k<<<dim3(32, 32), 256, 0, stream>>>(scb, rs, vtb, out);
}

// Round 3
// 651.393 us; speedup vs baseline: 1.3711x; 1.1857x over previous
//
#include <hip/hip_runtime.h>
#include <stdint.h>

// ---------------------------------------------------------------------------
// Decoder block: emb-gather+affine -> causal conv(K=3) -> relu -> GLU(softmax)
//                -> map matmul (+) cross-attention (QK^T softmax PV)
// Shapes: V=50257 E=256 H=256 2H=512 K=3 T=1024 B=32 S=1024 L=1023
// Output: (32, 1023, 512) f32
// R3: attention flash-fused (scores never materialized) + map-gemm epilogue
//     folded into the same kernel; XCD-swizzled grid for K/V L2 locality.
// Workspace layout (bytes):
//   Xbf   [32][1024][512] bf16 @ 0          (33,554,432)
//   Ybf   [32][1024][512] bf16 @ 33554432   (33,554,432)
//   dec   [32][1024][256] bf16 @ 67108864   (16,777,216)
//   encb  [32][1024][256] bf16 @ 83886080   (16,777,216)
//   vtb   [32][512][1024] bf16 @ 100663296  (33,554,432)  (V transposed)
//   wcb   [512][1536]     bf16 @ 134217728  ( 1,572,864)
//   mwb   [512][256]      bf16 @ 135790592  (   262,144)
//   awb   [512][256]      bf16 @ 136052736  (   262,144)
// ---------------------------------------------------------------------------

typedef __bf16 bf16x8_t __attribute__((ext_vector_type(8)));
typedef float  f32x4_t  __attribute__((ext_vector_type(4)));

#define DEV __device__ __forceinline__

DEV unsigned short f2bf(float f) {
  union { float f; unsigned u; } v; v.f = f;
  unsigned r = v.u + 0x7fffu + ((v.u >> 16) & 1u);
  return (unsigned short)(r >> 16);
}
DEV float bf2f(unsigned short u) {
  union { unsigned u; float f; } v; v.u = ((unsigned)u) << 16;
  return v.f;
}

// -------------------------- f32 -> bf16 copy -------------------------------
__global__ __launch_bounds__(256) void cvt_bf16_k(const float* __restrict__ src,
                                                  unsigned short* __restrict__ dst,
                                                  int n) {
  int i = (blockIdx.x * 256 + threadIdx.x) * 4;
  if (i >= n) return;
  float4 v = *(const float4*)(src + i);
  ushort4 o;
  o.x = f2bf(v.x); o.y = f2bf(v.y); o.z = f2bf(v.z); o.w = f2bf(v.w);
  *(ushort4*)(dst + i) = o;
}

// ------------------- V: f32 [b][s][d] -> bf16 [b][d][s] --------------------
__global__ __launch_bounds__(256) void cvt_transpose_v_k(const float* __restrict__ src,
                                                         unsigned short* __restrict__ dst) {
  __shared__ float tile[32][33];
  int b = blockIdx.z, s0 = blockIdx.x * 32, d0 = blockIdx.y * 32;
  int tx = threadIdx.x & 31, ty = threadIdx.x >> 5;
  const float* p = src + ((size_t)b * 1024 + s0) * 512 + d0;
  for (int r = ty; r < 32; r += 8) tile[r][tx] = p[(size_t)r * 512 + tx];
  __syncthreads();
  unsigned short* q = dst + ((size_t)b * 512 + d0) * 1024 + s0;
  for (int r = ty; r < 32; r += 8) q[(size_t)r * 1024 + tx] = f2bf(tile[tx][r]);
}

// ------ X[b][t][c] = bf16( emb[target[t,b]] @ affine_w^T + affine_b ) ------
__global__ __launch_bounds__(256) void embed_affine_k(const int* __restrict__ tgt,
                                                      const float* __restrict__ emb,
                                                      const unsigned short* __restrict__ awb,
                                                      const float* __restrict__ ab,
                                                      unsigned short* __restrict__ X) {
  constexpr int AP = 264;
  __shared__ unsigned short xs[32 * AP];
  const int r0 = blockIdx.x * 32;
  const int tid = threadIdx.x;
  for (int idx = tid; idx < 32 * 64; idx += 256) {
    int r = idx >> 6, c4 = (idx & 63) * 4;
    int row = tgt[r0 + r];
    float4 v = *(const float4*)&emb[(size_t)row * 256 + c4];
    ushort4 o;
    o.x = f2bf(v.x); o.y = f2bf(v.y); o.z = f2bf(v.z); o.w = f2bf(v.w);
    *(ushort4*)&xs[r * AP + c4] = o;
  }
  __syncthreads();
  const int lane = tid & 63, w = tid >> 6, q = lane >> 4, ln = lane & 15;
  f32x4_t acc[2][8];
#pragma unroll
  for (int mt = 0; mt < 2; ++mt)
#pragma unroll
    for (int nt = 0; nt < 8; ++nt) acc[mt][nt] = (f32x4_t){0.f, 0.f, 0.f, 0.f};
  for (int kk = 0; kk < 256; kk += 32) {
    bf16x8_t a[2], bb[8];
#pragma unroll
    for (int mt = 0; mt < 2; ++mt)
      a[mt] = *(const bf16x8_t*)(xs + (mt * 16 + ln) * AP + kk + q * 8);
#pragma unroll
    for (int nt = 0; nt < 8; ++nt) {
      int n = ((w * 8 + nt) << 4) + ln;
      bb[nt] = *(const bf16x8_t*)(awb + ((size_t)n << 8) + kk + q * 8);
    }
#pragma unroll
    for (int mt = 0; mt < 2; ++mt)
#pragma unroll
      for (int nt = 0; nt < 8; ++nt)
        acc[mt][nt] = __builtin_amdgcn_mfma_f32_16x16x32_bf16(a[mt], bb[nt], acc[mt][nt], 0, 0, 0);
  }
#pragma unroll
  for (int nt = 0; nt < 8; ++nt) {
    const int o = ((w * 8 + nt) << 4) + ln;
    const float bias = ab[o];
#pragma unroll
    for (int mt = 0; mt < 2; ++mt)
#pragma unroll
      for (int r = 0; r < 4; ++r) {
        int rid = r0 + mt * 16 + q * 4 + r;
        int t = rid >> 5, b = rid & 31;
        X[(((size_t)(b * 1024 + t)) << 9) + o] = f2bf(acc[mt][nt][r] + bias);
      }
  }
}

// ---- conv: Y[b][l][o] = relu(cb[o] + sum_{i,c} X[b][l-2+i][c] W[o][i*512+c])
__global__ __launch_bounds__(256) void conv_relu_k(const unsigned short* __restrict__ X,
                                                   const unsigned short* __restrict__ Wc,
                                                   const float* __restrict__ cb,
                                                   unsigned short* __restrict__ Y) {
  constexpr int LP = 520;
  __shared__ unsigned short xs[34 * LP];
  const int b = blockIdx.y, l0 = blockIdx.x * 32;
  const int tid = threadIdx.x;
  const int lane = tid & 63, w = tid >> 6, q = lane >> 4, ln = lane & 15;
  for (int idx = tid; idx < 34 * 64; idx += 256) {
    int r = idx >> 6, ch = idx & 63;
    int t = l0 - 2 + r;
    uint4 v = make_uint4(0u, 0u, 0u, 0u);
    if (t >= 0) v = *(const uint4*)(X + (((size_t)b * 1024 + t) << 9) + ch * 8);
    *(uint4*)(xs + r * LP + ch * 8) = v;
  }
  __syncthreads();
  f32x4_t acc[2][8];
#pragma unroll
  for (int mt = 0; mt < 2; ++mt)
#pragma unroll
    for (int nt = 0; nt < 8; ++nt) acc[mt][nt] = (f32x4_t){0.f, 0.f, 0.f, 0.f};
  for (int kk = 0; kk < 1536; kk += 32) {
    const int i = kk >> 9, c0 = kk & 511;
    bf16x8_t a[2], bb[8];
#pragma unroll
    for (int mt = 0; mt < 2; ++mt)
      a[mt] = *(const bf16x8_t*)(xs + (mt * 16 + ln + i) * LP + c0 + q * 8);
#pragma unroll
    for (int nt = 0; nt < 8; ++nt) {
      int o = ((w * 8 + nt) << 4) + ln;
      bb[nt] = *(const bf16x8_t*)(Wc + (size_t)o * 1536 + kk + q * 8);
    }
#pragma unroll
    for (int mt = 0; mt < 2; ++mt)
#pragma unroll
      for (int nt = 0; nt < 8; ++nt)
        acc[mt][nt] = __builtin_amdgcn_mfma_f32_16x16x32_bf16(a[mt], bb[nt], acc[mt][nt], 0, 0, 0);
  }
#pragma unroll
  for (int nt = 0; nt < 8; ++nt) {
    const int o = ((w * 8 + nt) << 4) + ln;
    const float bias = cb[o];
#pragma unroll
    for (int mt = 0; mt < 2; ++mt)
#pragma unroll
      for (int r = 0; r < 4; ++r) {
        int l = l0 + mt * 16 + q * 4 + r;
        float v = acc[mt][nt][r] + bias;
        Y[(((size_t)b * 1024 + l) << 9) + o] = f2bf(v > 0.f ? v : 0.f);
      }
  }
}

// ---- GLU: dec[b][l][h] = A[h] * softmax_h(Bg)[h], one wave per (b,l) row ---
__global__ __launch_bounds__(256) void glu_k(const unsigned short* __restrict__ Y,
                                             unsigned short* __restrict__ dec) {
  const int row = blockIdx.x * 4 + (threadIdx.x >> 6);
  const int lane = threadIdx.x & 63;
  const unsigned short* p = Y + ((size_t)row << 9);
  ushort4 av = *(const ushort4*)(p + lane * 4);
  ushort4 gv = *(const ushort4*)(p + 256 + lane * 4);
  float e0 = __expf(bf2f(gv.x)), e1 = __expf(bf2f(gv.y));
  float e2 = __expf(bf2f(gv.z)), e3 = __expf(bf2f(gv.w));
  float s = e0 + e1 + e2 + e3;
#pragma unroll
  for (int off = 32; off > 0; off >>= 1) s += __shfl_xor(s, off);
  float inv = 1.f / s;
  ushort4 o;
  o.x = f2bf(bf2f(av.x) * e0 * inv);
  o.y = f2bf(bf2f(av.y) * e1 * inv);
  o.z = f2bf(bf2f(av.z) * e2 * inv);
  o.w = f2bf(bf2f(av.w) * e3 * inv);
  *(ushort4*)(dec + ((size_t)row << 8) + lane * 4) = o;
}

// ---------------------------------------------------------------------------
// Fused attention + map epilogue:
//   out[b][l][:] = (exp(dec@enc^T) @ V) / rowsum + dec @ map_w^T + map_b
// One block = (b, 32 l-rows). 8 s-iters of 128; P via double-buffered LDS.
// Grid XCD-swizzled: all 32 l-tiles of a b stay on one XCD (enc+V ~1.5MB < L2).
// ---------------------------------------------------------------------------
__global__ __launch_bounds__(256) void attn_fused_k(const unsigned short* __restrict__ dec,
                                                    const unsigned short* __restrict__ enc,
                                                    const unsigned short* __restrict__ vt,
                                                    const unsigned short* __restrict__ mw,
                                                    const float* __restrict__ mb,
                                                    float* __restrict__ out) {
  constexpr int QP = 264;  // Q LDS stride (bf16): 528B -> 4-bank row skew
  constexpr int PP = 136;  // P LDS stride (bf16): 272B -> 4-bank row skew
  __shared__ unsigned short qs[32 * QP];
  __shared__ unsigned short ps[2][32 * PP];
  __shared__ float rws[4][32];
  __shared__ float rinv_s[32];

  const int bi = blockIdx.x;
  const int j = bi >> 3;
  const int b = ((bi & 7) << 2) | (j >> 5);  // same b -> same XCD (bi%8 const)
  const int l0 = (j & 31) << 5;
  const int tid = threadIdx.x;
  const int w = tid >> 6, lane = tid & 63, q = lane >> 4, ln = lane & 15;

  // stage Q = dec[b][l0:l0+32][0:256] into LDS (bf16)
  for (int idx = tid; idx < 32 * 32; idx += 256) {
    int r = idx >> 5, c8 = (idx & 31) * 8;
    *(uint4*)&qs[r * QP + c8] =
        *(const uint4*)(dec + (((size_t)b * 1024 + l0 + r) << 8) + c8);
  }
  __syncthreads();

  f32x4_t acc[2][8];
#pragma unroll
  for (int mt = 0; mt < 2; ++mt)
#pragma unroll
    for (int nt = 0; nt < 8; ++nt) acc[mt][nt] = (f32x4_t){0.f, 0.f, 0.f, 0.f};
  float prow[2][4];
#pragma unroll
  for (int mt = 0; mt < 2; ++mt)
#pragma unroll
    for (int r = 0; r < 4; ++r) prow[mt][r] = 0.f;

  const unsigned short* encB = enc + ((size_t)b << 18);  // [s][256]
  const unsigned short* vtB  = vt + ((size_t)b << 19);   // [d][1024]

  for (int it = 0; it < 8; ++it) {
    const int s0 = it << 7;
    const int sw = s0 + (w << 5);  // this wave's 32-s slice
    // ---- QK^T: S(32l x 32s) per wave ----
    f32x4_t sacc[2][2];
#pragma unroll
    for (int mt = 0; mt < 2; ++mt)
#pragma unroll
      for (int nt = 0; nt < 2; ++nt) sacc[mt][nt] = (f32x4_t){0.f, 0.f, 0.f, 0.f};
    for (int kk = 0; kk < 256; kk += 32) {
      bf16x8_t a[2], bb[2];
#pragma unroll
      for (int mt = 0; mt < 2; ++mt)
        a[mt] = *(const bf16x8_t*)(qs + (mt * 16 + ln) * QP + kk + q * 8);
#pragma unroll
      for (int nt = 0; nt < 2; ++nt)
        bb[nt] = *(const bf16x8_t*)(encB + (((size_t)(sw + nt * 16 + ln)) << 8) + kk + q * 8);
#pragma unroll
      for (int mt = 0; mt < 2; ++mt)
#pragma unroll
        for (int nt = 0; nt < 2; ++nt)
          sacc[mt][nt] = __builtin_amdgcn_mfma_f32_16x16x32_bf16(a[mt], bb[nt], sacc[mt][nt], 0, 0, 0);
    }
    // ---- exp (f32), rowsum partials, P -> LDS (A-operand layout source) ----
    unsigned short* pb = ps[it & 1];
#pragma unroll
    for (int mt = 0; mt < 2; ++mt)
#pragma unroll
      for (int nt = 0; nt < 2; ++nt)
#pragma unroll
        for (int r = 0; r < 4; ++r) {
          float e = __expf(sacc[mt][nt][r]);
          prow[mt][r] += e;
          pb[(mt * 16 + q * 4 + r) * PP + (w << 5) + nt * 16 + ln] = f2bf(e);
        }
    __syncthreads();
    // ---- PV: acc += P(32x128) @ V(128 x 128-per-wave) ----
#pragma unroll
    for (int kt = 0; kt < 4; ++kt) {
      bf16x8_t a[2], bb[8];
#pragma unroll
      for (int mt = 0; mt < 2; ++mt)
        a[mt] = *(const bf16x8_t*)(pb + (mt * 16 + ln) * PP + kt * 32 + q * 8);
#pragma unroll
      for (int nt = 0; nt < 8; ++nt) {
        int d = (w << 7) + nt * 16 + ln;
        bb[nt] = *(const bf16x8_t*)(vtB + (((size_t)d) << 10) + s0 + kt * 32 + q * 8);
      }
#pragma unroll
      for (int mt = 0; mt < 2; ++mt)
#pragma unroll
        for (int nt = 0; nt < 8; ++nt)
          acc[mt][nt] = __builtin_amdgcn_mfma_f32_16x16x32_bf16(a[mt], bb[nt], acc[mt][nt], 0, 0, 0);
    }
  }

  // ---- rowsum: reduce per-lane partials over the 16 ln lanes ----
#pragma unroll
  for (int mt = 0; mt < 2; ++mt)
#pragma unroll
    for (int r = 0; r < 4; ++r) {
      float v = prow[mt][r];
      v += __shfl_xor(v, 1); v += __shfl_xor(v, 2);
      v += __shfl_xor(v, 4); v += __shfl_xor(v, 8);
      if (ln == 0) rws[w][mt * 16 + q * 4 + r] = v;
    }
  __syncthreads();
  if (tid < 32)
    rinv_s[tid] = 1.f / (rws[0][tid] + rws[1][tid] + rws[2][tid] + rws[3][tid]);
  __syncthreads();

  float ri[2][4];
#pragma unroll
  for (int mt = 0; mt < 2; ++mt)
#pragma unroll
    for (int r = 0; r < 4; ++r) ri[mt][r] = rinv_s[mt * 16 + q * 4 + r];
#pragma unroll
  for (int mt = 0; mt < 2; ++mt)
#pragma unroll
    for (int nt = 0; nt < 8; ++nt)
#pragma unroll
      for (int r = 0; r < 4; ++r) acc[mt][nt][r] *= ri[mt][r];

  // ---- map epilogue: acc += dec_tile @ map_w^T (A-frags from qs) ----
  for (int kk = 0; kk < 256; kk += 32) {
    bf16x8_t a[2], bb[8];
#pragma unroll
    for (int mt = 0; mt < 2; ++mt)
      a[mt] = *(const bf16x8_t*)(qs + (mt * 16 + ln) * QP + kk + q * 8);
#pragma unroll
    for (int nt = 0; nt < 8; ++nt) {
      int n = (w << 7) + nt * 16 + ln;
      bb[nt] = *(const bf16x8_t*)(mw + ((size_t)n << 8) + kk + q * 8);
    }
#pragma unroll
    for (int mt = 0; mt < 2; ++mt)
#pragma unroll
      for (int nt = 0; nt < 8; ++nt)
        acc[mt][nt] = __builtin_amdgcn_mfma_f32_16x16x32_bf16(a[mt], bb[nt], acc[mt][nt], 0, 0, 0);
  }

  // ---- store out (f32), skipping l == 1023 ----
#pragma unroll
  for (int nt = 0; nt < 8; ++nt) {
    const int d = (w << 7) + nt * 16 + ln;
    const float bias = mb[d];
#pragma unroll
    for (int mt = 0; mt < 2; ++mt)
#pragma unroll
      for (int r = 0; r < 4; ++r) {
        int l = l0 + mt * 16 + q * 4 + r;
        if (l < 1023) out[((size_t)b * 1023 + l) * 512 + d] = acc[mt][nt][r] + bias;
      }
  }
}

// ---------------------------------------------------------------------------
extern "C" void kernel_launch(void* const* d_in, const int* in_sizes, int n_in,
                              void* d_out, int out_size, void* d_ws, size_t ws_size,
                              hipStream_t stream) {
  const int*   target = (const int*)d_in[1];
  const float* enc    = (const float*)d_in[2];
  const float* src    = (const float*)d_in[3];
  const float* emb    = (const float*)d_in[4];
  const float* aw     = (const float*)d_in[5];
  const float* ab     = (const float*)d_in[6];
  const float* cw     = (const float*)d_in[7];
  const float* cb     = (const float*)d_in[8];
  const float* mw     = (const float*)d_in[9];
  const float* mb     = (const float*)d_in[10];
  float* out = (float*)d_out;
  char* ws = (char*)d_ws;

  unsigned short* Xbf  = (unsigned short*)(ws);
  unsigned short* Ybf  = (unsigned short*)(ws + 33554432);
  unsigned short* dec  = (unsigned short*)(ws + 67108864);
  unsigned short* encb = (unsigned short*)(ws + 83886080);
  unsigned short* vtb  = (unsigned short*)(ws + 100663296);
  unsigned short* wcb  = (unsigned short*)(ws + 134217728);
  unsigned short* mwb  = (unsigned short*)(ws + 135790592);
  unsigned short* awb  = (unsigned short*)(ws + 136052736);

  cvt_bf16_k<<<8192, 256, 0, stream>>>(enc, encb, 32 * 1024 * 256);
  cvt_bf16_k<<<768, 256, 0, stream>>>(cw, wcb, 512 * 1536);
  cvt_bf16_k<<<128, 256, 0, stream>>>(mw, mwb, 512 * 256);
  cvt_bf16_k<<<128, 256, 0, stream>>>(aw, awb, 512 * 256);
  cvt_transpose_v_k<<<dim3(32, 16, 32), 256, 0, stream>>>(src, vtb);
  embed_affine_k<<<1024, 256, 0, stream>>>(target, emb, awb, ab, Xbf);
  conv_relu_k<<<dim3(32, 32), 256, 0, stream>>>(Xbf, wcb, cb, Ybf);
  glu_k<<<8192, 256, 0, stream>>>(Ybf, dec);
  attn_fused_k<<<1024, 256, 0, stream>>>(dec, encb, vtb, mwb, mb, out);
}